// Round 1
// baseline (2421.002 us; speedup 1.0000x reference)
//
#include <hip/hip_runtime.h>
#include <hip/hip_bf16.h>

#define NN 20000
#define NP 20032            // padded to 32*626
#define NE 320000
#define RR 8
#define DD 256
#define LL 6
#define EED 32
#define BB 64
#define KK 32
#define MM (NN * RR)        // 160000 segments, key = dst*8 + rel
#define NSB 79              // scan blocks: ceil(160000 / 2048)
#define NB2 626             // row blocks of 32
#define HSTR 260            // padded h-tile row stride (floats)
#define ES_CAP 1280         // per-block staged edge-list capacity (avg 512, max ~650)

typedef __bf16 bf8 __attribute__((ext_vector_type(8)));
typedef float f4 __attribute__((ext_vector_type(4)));

__device__ inline float lo2f(unsigned v) { return __uint_as_float(v << 16); }
__device__ inline float hi2f(unsigned v) { return __uint_as_float(v & 0xffff0000u); }
__device__ inline unsigned short f2bf(float f) {
    unsigned u = __float_as_uint(f);
    return (unsigned short)((u + 0x7fff + ((u >> 16) & 1)) >> 16);
}
__device__ inline unsigned pack2(float lo, float hi) {
    return (unsigned)f2bf(lo) | ((unsigned)f2bf(hi) << 16);
}

// ---------------- CSR build (once per call) ----------------

__global__ __launch_bounds__(256) void hist_kernel(const int* __restrict__ dstv,
                                                   const int* __restrict__ typev,
                                                   int* __restrict__ hist) {
    int e = blockIdx.x * 256 + threadIdx.x;
    if (e < NE) atomicAdd(&hist[dstv[e] * 8 + typev[e]], 1);
}

__global__ __launch_bounds__(256) void scan1_kernel(const int* __restrict__ hist,
                                                    int* __restrict__ excl,
                                                    int* __restrict__ bsums) {
    __shared__ int tmp[256];
    int tid = threadIdx.x;
    int base = blockIdx.x * 2048 + tid * 8;
    int v[8]; int s = 0;
#pragma unroll
    for (int i = 0; i < 8; ++i) {
        v[i] = (base + i < MM) ? hist[base + i] : 0;
        s += v[i];
    }
    tmp[tid] = s;
    __syncthreads();
    for (int off = 1; off < 256; off <<= 1) {
        int t = (tid >= off) ? tmp[tid - off] : 0;
        __syncthreads();
        tmp[tid] += t;
        __syncthreads();
    }
    int run = tmp[tid] - s;
#pragma unroll
    for (int i = 0; i < 8; ++i) {
        if (base + i < MM) excl[base + i] = run;
        run += v[i];
    }
    if (tid == 255) bsums[blockIdx.x] = tmp[255];
}

__global__ __launch_bounds__(128) void scan2_kernel(int* __restrict__ bsums) {
    __shared__ int tmp[128];
    int tid = threadIdx.x;
    int orig = (tid < NSB) ? bsums[tid] : 0;
    tmp[tid] = orig;
    __syncthreads();
    for (int off = 1; off < 128; off <<= 1) {
        int t = (tid >= off) ? tmp[tid - off] : 0;
        __syncthreads();
        tmp[tid] += t;
        __syncthreads();
    }
    if (tid < NSB) bsums[tid] = tmp[tid] - orig;
}

__global__ __launch_bounds__(256) void add_off_kernel(const int* __restrict__ excl,
                                                      const int* __restrict__ bsums,
                                                      int* __restrict__ seg_start,
                                                      int* __restrict__ cursor) {
    int i = blockIdx.x * 256 + threadIdx.x;
    if (i < MM) {
        int v = excl[i] + bsums[i >> 11];
        seg_start[i] = v;
        cursor[i] = v;
    }
    if (i == 0) seg_start[MM] = NE;
}

__global__ __launch_bounds__(256) void sort_scatter_kernel(
    const int* __restrict__ srcv, const int* __restrict__ dstv,
    const int* __restrict__ typev, int* __restrict__ cursor,
    int* __restrict__ esrc, int* __restrict__ eid) {
    int e = blockIdx.x * 256 + threadIdx.x;
    if (e < NE) {
        int key = dstv[e] * 8 + typev[e];
        int pos = atomicAdd(&cursor[key], 1);
        esrc[pos] = srcv[e];
        eid[pos]  = e;
    }
}

__global__ __launch_bounds__(256) void invdeg_kernel(const int* __restrict__ seg_start,
                                                     float* __restrict__ invdeg) {
    int i = blockIdx.x * 256 + threadIdx.x;
    if (i < NN) {
        int d = seg_start[i * 8 + 8] - seg_start[i * 8];
        invdeg[i] = 1.0f / (float)max(d, 1);
    }
}

// ---------------- once-per-call precomputes ----------------

__global__ __launch_bounds__(256) void eagg_kernel(
    const int* __restrict__ seg_start, const int* __restrict__ eid,
    const float* __restrict__ ee, const float* __restrict__ invdeg,
    unsigned short* __restrict__ eaggbf) {
    int tid = threadIdx.x;
    int s = blockIdx.x * 8 + (tid >> 5);
    int j = tid & 31;
    int n = s >> 3, r = s & 7;
    int j0 = seg_start[s], j1 = seg_start[s + 1];
    float sum = 0.0f;
    for (int p = j0; p < j1; ++p)
        sum += ee[eid[p] * EED + j];
    eaggbf[(size_t)n * DD + r * EED + j] = f2bf(sum * invdeg[n]);
}

// Whe split-K over 8 d-chunks of 32, fp32 atomics (Whe pre-zeroed)
__global__ __launch_bounds__(256) void whe_kernel(const float* __restrict__ We,
                                                  const float* __restrict__ W,
                                                  float* __restrict__ Whe) {
    __shared__ float WeS[EED * 32];
    int b = blockIdx.x;
    int l = b >> 6;
    int r = (b >> 3) & 7;
    int dc = b & 7;
    int tid = threadIdx.x;
    {
        int j = tid >> 3, dl = (tid & 7) * 4;
        *(float4*)&WeS[j * 32 + dl] =
            *(const float4*)&We[(size_t)l * EED * DD + (size_t)j * DD + dc * 32 + dl];
    }
    __syncthreads();
    const float* Wr = W + ((size_t)l * 8 + r) * DD * DD + (size_t)dc * 32 * DD;
    float acc[EED];
#pragma unroll
    for (int j = 0; j < EED; ++j) acc[j] = 0.0f;
    for (int dl = 0; dl < 32; ++dl) {
        float w = Wr[(size_t)dl * DD + tid];
#pragma unroll
        for (int j = 0; j < EED; ++j) acc[j] += WeS[j * 32 + dl] * w;
    }
    float* outp = Whe + (size_t)l * DD * DD + r * EED * DD + tid;
#pragma unroll
    for (int j = 0; j < EED; ++j) unsafeAtomicAdd(&outp[j * DD], acc[j]);
}

// B pre-swizzle into MFMA fragment order (bf16).
// Phase order: p=0 -> Wself, p=1..8 -> W[r=p-1], p=9 -> Whe.
// Bsw[l][(((p*8+kb)*4+quad)*256+f)*8+j] = B_l[p][kb*32+quad*8+j][f]
__global__ __launch_bounds__(256) void bswz_kernel(const float* __restrict__ W,
                                                   const float* __restrict__ Wself,
                                                   const float* __restrict__ Whe,
                                                   unsigned short* __restrict__ Bsw) {
    int gid = blockIdx.x * 256 + threadIdx.x;
    int f = gid & 255;
    int t = gid >> 8;
    int quad = t & 3; t >>= 2;
    int kb = t & 7; t >>= 3;
    int p = t % 10, l = t / 10;
    const float* base = (p == 0) ? Wself + (size_t)l * DD * DD
                      : (p <= 8) ? W + ((size_t)l * 8 + (p - 1)) * DD * DD
                                 : Whe + (size_t)l * DD * DD;
    int k0 = kb * 32 + quad * 8;
    unsigned pk[4];
#pragma unroll
    for (int jj = 0; jj < 4; ++jj)
        pk[jj] = pack2(base[(size_t)(k0 + 2 * jj) * DD + f],
                       base[(size_t)(k0 + 2 * jj + 1) * DD + f]);
    uint4 v = make_uint4(pk[0], pk[1], pk[2], pk[3]);
    *(uint4*)&Bsw[(size_t)gid * 8] = v;
}

__global__ __launch_bounds__(256) void init_x_kernel(float* __restrict__ x,
                                                     unsigned short* __restrict__ xbf) {
    int i = blockIdx.x * 256 + threadIdx.x;
    ((float4*)x)[i] = make_float4(1.f, 1.f, 1.f, 1.f);
    ((uint2*)xbf)[i] = make_uint2(0x3f803f80u, 0x3f803f80u);
}

// ------- fused per-layer kernel: producer/consumer waves, gather + MFMA + LN -------
// Block = 32 dst rows x 256 cols, 8 waves (512 thr):
//   waves 0..3 (CONSUMERS): MFMA on buf[p], cols cwave*64..+63, B fragments
//     register-prefetched 2 g-steps ahead from pre-swizzled Bsw.
//   waves 4..7 (PRODUCERS): cross-phase software pipeline. At iteration p they
//     ACCUMULATE the gather batch for phase p+1 (loads issued one phase earlier)
//     and immediately RE-ISSUE that row's 4 slots for the next relation, so every
//     batch gets a full phase (~consumer MFMA window) of latency budget.
// Phase barriers are raw s_barrier + lgkmcnt(0) only (NO vmcnt drain): in-flight
// gather loads and consumer B-prefetches survive the barrier (T14/m201 pattern).
// Rolling bounds: j1(rel r) == j0(rel r+1), so 1 LDS read per row per phase.
// eagg (phase 9) is staged once in the prologue into a 3rd buffer.
// LDS: 3x16KB phase buffers + 1040B bounds + ES_CAP*4 edge srcs = 55312B -> 2 blk/CU.
// __launch_bounds__(512,4): force total (arch+acc) regs <= 128 so 2 blocks co-reside.
__global__ __launch_bounds__(512, 4) void fused_layer_kernel(
    const int* __restrict__ seg_start, const int* __restrict__ esrc,
    const unsigned short* __restrict__ xbf, const unsigned short* __restrict__ eaggbf,
    const unsigned short* __restrict__ Bswl, const float* __restrict__ xin,
    const float* __restrict__ gl, const float* __restrict__ bl,
    float* __restrict__ xout, unsigned short* __restrict__ xbfout) {
    __shared__ __align__(16) unsigned char smem[49152 + 1040 + ES_CAP * 4];
    float* Hs = (float*)smem;                       // epilogue overlay (32 x HSTR)
    int* boundsS = (int*)(smem + 49152);            // 257 seg bounds
    int* esrcS   = (int*)(smem + 49152 + 1040);     // staged edge srcs
    int tid = threadIdx.x;
    int wave = tid >> 6, lane = tid & 63;
    bool consumer = wave < 4;
    int cwave = wave & 3;                           // consumer col group / producer row group
    int row0 = blockIdx.x * 32;
    int m = lane & 15, quad = lane >> 4;
    int colg = lane >> 1, half = lane & 1, cofs = lane * 4;
    f4 acc[2][4] = {};

    // ---- prologue: bounds, x tile, eagg tile, edge list, B prefetch ----
    if (tid < 257) {
        int idx = row0 * 8 + tid;
        boundsS[tid] = (idx <= MM) ? seg_start[idx] : NE;   // pad rows -> empty
    }
    uint4 xs[2];
#pragma unroll
    for (int c = 0; c < 2; ++c) {
        int i = tid + c * 512;
        int row = i >> 5, sc = i & 31;
        xs[c] = *(const uint4*)&xbf[(size_t)(row0 + row) * DD + sc * 8];
    }
    uint4 ev[4];
    if (!consumer) {
#pragma unroll
        for (int it = 0; it < 4; ++it) {
            int row = cwave * 8 + it * 2 + (lane >> 5);
            int sc = lane & 31;
            ev[it] = *(const uint4*)&eaggbf[(size_t)(row0 + row) * DD + sc * 8];
        }
    }
    __syncthreads();                                // bounds visible
    int blk0 = boundsS[0];
    int blkE = boundsS[256] - blk0;
    for (int j = tid; j < ES_CAP; j += 512)
        esrcS[j] = (j < blkE) ? esrc[blk0 + j] : 0; // always-valid node ids
#pragma unroll
    for (int c = 0; c < 2; ++c) {
        int i = tid + c * 512;
        int row = i >> 5, sc = i & 31;
        *(uint4*)&smem[row * 512 + ((sc ^ row) * 16)] = xs[c];     // x -> buf0
    }
    int jroll[8];
    float idgr[8];
    if (!consumer) {
#pragma unroll
        for (int it = 0; it < 4; ++it) {            // eagg -> buf2
            int row = cwave * 8 + it * 2 + (lane >> 5);
            int sc = lane & 31;
            *(uint4*)&smem[32768 + row * 512 + ((sc ^ row) * 16)] = ev[it];
        }
#pragma unroll
        for (int i8 = 0; i8 < 8; ++i8) {
            int nl = cwave * 8 + i8;
            jroll[i8] = boundsS[nl * 8] - blk0;     // j0 of relation 0
            int dg = boundsS[nl * 8 + 8] - boundsS[nl * 8];
            idgr[i8] = 1.0f / (float)max(dg, 1);
        }
    }
    bf8 breg[2][4];
    if (consumer) {
#pragma unroll
        for (int nt = 0; nt < 4; ++nt) {
            breg[0][nt] = *(const bf8*)&Bswl[((size_t)quad * 256 + cwave * 64 + nt * 16 + m) * 8];
            breg[1][nt] = *(const bf8*)&Bswl[((size_t)(4 + quad) * 256 + cwave * 64 + nt * 16 + m) * 8];
        }
    }
    __syncthreads();                                // esrcS + buf0 + buf2 visible

    // issue relation-0 gather batch (consumed at iteration p=0)
    uint2 gv[8][4];
    if (!consumer) {
#pragma unroll
        for (int i8 = 0; i8 < 8; ++i8) {
#pragma unroll
            for (int s = 0; s < 4; ++s) {
                int jc = jroll[i8] + s;
                jc = (jc < ES_CAP) ? jc : (ES_CAP - 1);
                gv[i8][s] = *(const uint2*)&xbf[(size_t)esrcS[jc] * DD + cofs];
            }
        }
    }

#pragma unroll
    for (int p = 0; p < 10; ++p) {
        if (consumer) {
            // ---- 8 MFMA steps on buf[p]; B register-prefetch 2 steps ahead ----
            unsigned char* bufp = smem + ((p == 9) ? 2 : (p & 1)) * 16384;
#pragma unroll
            for (int kb = 0; kb < 8; ++kb) {
                bf8 afr[2];
#pragma unroll
                for (int mt = 0; mt < 2; ++mt) {
                    int rowl = mt * 16 + m;
                    afr[mt] = *(bf8*)&bufp[rowl * 512 + (((kb * 4 + quad) ^ rowl) * 16)];
                }
#pragma unroll
                for (int mt = 0; mt < 2; ++mt)
#pragma unroll
                    for (int nt = 0; nt < 4; ++nt)
                        acc[mt][nt] = __builtin_amdgcn_mfma_f32_16x16x32_bf16(
                            afr[mt], breg[kb & 1][nt], acc[mt][nt], 0, 0, 0);
                int gn = p * 8 + kb + 2;
                if (gn < 80) {
#pragma unroll
                    for (int nt = 0; nt < 4; ++nt)
                        breg[kb & 1][nt] = *(const bf8*)&Bswl[((size_t)gn * 4 + quad) * 2048
                                                              + ((size_t)(cwave * 64 + nt * 16 + m)) * 8];
                }
            }
        } else if (p < 8) {
            // ---- producer: finish relation p (phase q=p+1) into buf[q&1];
            //      per row, immediately re-issue next relation's 4 slots ----
            int q = p + 1;
            unsigned char* bufn = smem + ((q & 1) * 16384);
#pragma unroll
            for (int i8 = 0; i8 < 8; ++i8) {
                int nl = cwave * 8 + i8;
                int j0 = jroll[i8];
                int j1 = boundsS[nl * 8 + q] - blk0;   // end of relation p = start of p+1
                float a0 = 0.f, a1 = 0.f, a2 = 0.f, a3 = 0.f;
#pragma unroll
                for (int s = 0; s < 4; ++s) {
                    unsigned vx = (j0 + s < j1) ? gv[i8][s].x : 0u;
                    unsigned vy = (j0 + s < j1) ? gv[i8][s].y : 0u;
                    a0 += lo2f(vx); a1 += hi2f(vx);
                    a2 += lo2f(vy); a3 += hi2f(vy);
                }
                if (q < 8) {                            // issue next-relation batch
#pragma unroll
                    for (int s = 0; s < 4; ++s) {
                        int jc = j1 + s;
                        jc = (jc < ES_CAP) ? jc : (ES_CAP - 1);
                        gv[i8][s] = *(const uint2*)&xbf[(size_t)esrcS[jc] * DD + cofs];
                    }
                }
                for (int j = j0 + 4; j < j1; ++j) {     // rare tail (>4 edges/seg)
                    int src = (j < ES_CAP) ? esrcS[j] : esrc[blk0 + j];
                    uint2 v = *(const uint2*)&xbf[(size_t)src * DD + cofs];
                    a0 += lo2f(v.x); a1 += hi2f(v.x);
                    a2 += lo2f(v.y); a3 += hi2f(v.y);
                }
                float idg = idgr[i8];
                *(uint2*)&bufn[nl * 512 + ((colg ^ nl) * 16) + half * 8] =
                    make_uint2(pack2(a0 * idg, a1 * idg), pack2(a2 * idg, a3 * idg));
                jroll[i8] = j1;
            }
        }
        // raw phase barrier: drain LDS writes only, keep VMEM (gathers + B prefetch)
        // in flight across the barrier. sched_barrier fences scheduler motion (#18).
        asm volatile("s_waitcnt lgkmcnt(0)" ::: "memory");
        __builtin_amdgcn_s_barrier();
        __builtin_amdgcn_sched_barrier(0);
    }

    // ---- epilogue: residual prefetch; h tile through LDS; LN+ReLU+residual ----
    float4 xvr[4];
#pragma unroll
    for (int rr = 0; rr < 4; ++rr) {
        int row = wave * 4 + rr;
        xvr[rr] = *(const float4*)&xin[(size_t)(row0 + row) * DD + lane * 4];
    }
    float4 g  = *(const float4*)&gl[lane * 4];
    float4 bb = *(const float4*)&bl[lane * 4];
    if (consumer) {
#pragma unroll
        for (int mt = 0; mt < 2; ++mt)
#pragma unroll
            for (int nt = 0; nt < 4; ++nt)
#pragma unroll
                for (int rg = 0; rg < 4; ++rg)
                    Hs[(mt * 16 + quad * 4 + rg) * HSTR + cwave * 64 + nt * 16 + m] = acc[mt][nt][rg];
    }
    __syncthreads();
#pragma unroll
    for (int rr = 0; rr < 4; ++rr) {
        int row = wave * 4 + rr;
        float4 v = *(float4*)&Hs[row * HSTR + lane * 4];
        float s = v.x + v.y + v.z + v.w;
        float q = v.x * v.x + v.y * v.y + v.z * v.z + v.w * v.w;
#pragma unroll
        for (int off = 32; off; off >>= 1) {
            s += __shfl_xor(s, off);
            q += __shfl_xor(q, off);
        }
        float mu  = s * (1.0f / DD);
        float var = q * (1.0f / DD) - mu * mu;
        float rs  = rsqrtf(var + 1e-5f);
        size_t xi = (size_t)(row0 + row) * DD + lane * 4;
        float4 xv = xvr[rr];
        float4 o;
        o.x = fmaxf((v.x - mu) * rs * g.x + bb.x, 0.0f) + xv.x;
        o.y = fmaxf((v.y - mu) * rs * g.y + bb.y, 0.0f) + xv.y;
        o.z = fmaxf((v.z - mu) * rs * g.z + bb.z, 0.0f) + xv.z;
        o.w = fmaxf((v.w - mu) * rs * g.w + bb.w, 0.0f) + xv.w;
        *(float4*)&xout[xi] = o;
        *(uint2*)&xbfout[xi] = make_uint2(pack2(o.x, o.y), pack2(o.z, o.w));
    }
}

__global__ __launch_bounds__(256) void score_kernel(
    const int* __restrict__ batch, const float* __restrict__ x,
    const float* __restrict__ rel_emb, float* __restrict__ out) {
    int tid = threadIdx.x;
    int wave = tid >> 6, lane = tid & 63;
    int idx = blockIdx.x * 4 + wave;
    int s = batch[idx * 3 + 0], t = batch[idx * 3 + 1], r = batch[idx * 3 + 2];
    float4 sv = *(const float4*)&x[(size_t)s * DD + lane * 4];
    float4 tv = *(const float4*)&x[(size_t)t * DD + lane * 4];
    float4 rv = *(const float4*)&rel_emb[(size_t)r * DD + lane * 4];
    float sum = sv.x * rv.x * tv.x + sv.y * rv.y * tv.y +
                sv.z * rv.z * tv.z + sv.w * rv.w * tv.w;
#pragma unroll
    for (int off = 32; off; off >>= 1) sum += __shfl_xor(sum, off);
    if (lane == 0) out[idx] = sum;
}

extern "C" void kernel_launch(void* const* d_in, const int* in_sizes, int n_in,
                              void* d_out, int out_size, void* d_ws, size_t ws_size,
                              hipStream_t stream) {
    const int*   edge_index = (const int*)d_in[0];
    const int*   srcv   = edge_index;
    const int*   dstv   = edge_index + NE;
    const int*   typev  = (const int*)d_in[1];
    const float* ee     = (const float*)d_in[2];
    const int*   batch  = (const int*)d_in[3];
    const float* W      = (const float*)d_in[4];
    const float* Wself  = (const float*)d_in[5];
    const float* We     = (const float*)d_in[6];
    const float* gamma  = (const float*)d_in[7];
    const float* beta   = (const float*)d_in[8];
    const float* rel_emb= (const float*)d_in[9];
    float* out = (float*)d_out;

    // workspace layout
    float* xA     = (float*)d_ws;                          // NP*256 f32
    float* xB     = xA + (size_t)NP * DD;                  // NP*256 f32
    float* Whe    = xB + (size_t)NP * DD;                  // L*256*256 f32
    float* invdeg = Whe + (size_t)LL * DD * DD;            // NN f32
    unsigned short* xbfA   = (unsigned short*)(invdeg + NN);          // NP*256
    unsigned short* xbfB   = xbfA + (size_t)NP * DD;                  // NP*256
    unsigned short* eaggbf = xbfB + (size_t)NP * DD;                  // NP*256
    unsigned short* Bsw    = eaggbf + (size_t)NP * DD;                // L*2560*256
    int* hist      = (int*)(Bsw + (size_t)LL * 2560 * DD);            // M
    int* excl      = hist + MM;
    int* seg_start = excl + MM;                                       // M+1
    int* cursor    = seg_start + MM + 1;
    int* bsums     = cursor + MM;                                     // 256
    int* esrc      = bsums + 256;                                     // E
    int* eid       = esrc + NE;                                       // E

    // ---- CSR build ----
    hipMemsetAsync(hist, 0, MM * sizeof(int), stream);
    hist_kernel<<<(NE + 255) / 256, 256, 0, stream>>>(dstv, typev, hist);
    scan1_kernel<<<NSB, 256, 0, stream>>>(hist, excl, bsums);
    scan2_kernel<<<1, 128, 0, stream>>>(bsums);
    add_off_kernel<<<(MM + 255) / 256, 256, 0, stream>>>(excl, bsums, seg_start, cursor);
    invdeg_kernel<<<(NN + 255) / 256, 256, 0, stream>>>(seg_start, invdeg);
    sort_scatter_kernel<<<(NE + 255) / 256, 256, 0, stream>>>(srcv, dstv, typev, cursor, esrc, eid);

    // ---- precomputes ----
    eagg_kernel<<<MM / 8, 256, 0, stream>>>(seg_start, eid, ee, invdeg, eaggbf);
    hipMemsetAsync(Whe, 0, (size_t)LL * DD * DD * sizeof(float), stream);
    whe_kernel<<<LL * 64, 256, 0, stream>>>(We, W, Whe);
    bswz_kernel<<<LL * 10 * 8 * 4, 256, 0, stream>>>(W, Wself, Whe, Bsw);
    init_x_kernel<<<(NP * DD / 4) / 256, 256, 0, stream>>>(xA, xbfA);

    // ---- layers (x double-buffered), producer/consumer fused kernel ----
    float* xin = xA;  float* xout = xB;
    unsigned short* xbin = xbfA;  unsigned short* xbout = xbfB;
    for (int l = 0; l < LL; ++l) {
        fused_layer_kernel<<<NB2, 512, 0, stream>>>(seg_start, esrc, xbin, eaggbf,
            Bsw + (size_t)l * 2560 * DD, xin,
            gamma + (size_t)l * DD, beta + (size_t)l * DD, xout, xbout);
        float* t = xin; xin = xout; xout = t;
        unsigned short* tb = xbin; xbin = xbout; xbout = tb;
    }
    score_kernel<<<(BB * KK) / 4, 256, 0, stream>>>(batch, xin, rel_emb, out);
}

// Round 2
// 927.315 us; speedup vs baseline: 2.6108x; 2.6108x over previous
//
#include <hip/hip_runtime.h>
#include <hip/hip_bf16.h>

#define NN 20000
#define NP 20032            // padded to 32*626
#define NE 320000
#define RR 8
#define DD 256
#define LL 6
#define EED 32
#define BB 64
#define KK 32
#define MM (NN * RR)        // 160000 segments, key = dst*8 + rel
#define NSB 79              // scan blocks: ceil(160000 / 2048)
#define NB2 626             // row blocks of 32
#define HSTR 260            // padded h-tile row stride (floats)
#define ES_CAP 1280         // per-block staged edge-list capacity (avg 512, max ~650)

typedef __bf16 bf8 __attribute__((ext_vector_type(8)));
typedef float f4 __attribute__((ext_vector_type(4)));

__device__ inline float lo2f(unsigned v) { return __uint_as_float(v << 16); }
__device__ inline float hi2f(unsigned v) { return __uint_as_float(v & 0xffff0000u); }
__device__ inline unsigned short f2bf(float f) {
    unsigned u = __float_as_uint(f);
    return (unsigned short)((u + 0x7fff + ((u >> 16) & 1)) >> 16);
}
__device__ inline unsigned pack2(float lo, float hi) {
    return (unsigned)f2bf(lo) | ((unsigned)f2bf(hi) << 16);
}

// ---------------- CSR build (once per call) ----------------

__global__ __launch_bounds__(256) void hist_kernel(const int* __restrict__ dstv,
                                                   const int* __restrict__ typev,
                                                   int* __restrict__ hist) {
    int e = blockIdx.x * 256 + threadIdx.x;
    if (e < NE) atomicAdd(&hist[dstv[e] * 8 + typev[e]], 1);
}

__global__ __launch_bounds__(256) void scan1_kernel(const int* __restrict__ hist,
                                                    int* __restrict__ excl,
                                                    int* __restrict__ bsums) {
    __shared__ int tmp[256];
    int tid = threadIdx.x;
    int base = blockIdx.x * 2048 + tid * 8;
    int v[8]; int s = 0;
#pragma unroll
    for (int i = 0; i < 8; ++i) {
        v[i] = (base + i < MM) ? hist[base + i] : 0;
        s += v[i];
    }
    tmp[tid] = s;
    __syncthreads();
    for (int off = 1; off < 256; off <<= 1) {
        int t = (tid >= off) ? tmp[tid - off] : 0;
        __syncthreads();
        tmp[tid] += t;
        __syncthreads();
    }
    int run = tmp[tid] - s;
#pragma unroll
    for (int i = 0; i < 8; ++i) {
        if (base + i < MM) excl[base + i] = run;
        run += v[i];
    }
    if (tid == 255) bsums[blockIdx.x] = tmp[255];
}

__global__ __launch_bounds__(128) void scan2_kernel(int* __restrict__ bsums) {
    __shared__ int tmp[128];
    int tid = threadIdx.x;
    int orig = (tid < NSB) ? bsums[tid] : 0;
    tmp[tid] = orig;
    __syncthreads();
    for (int off = 1; off < 128; off <<= 1) {
        int t = (tid >= off) ? tmp[tid - off] : 0;
        __syncthreads();
        tmp[tid] += t;
        __syncthreads();
    }
    if (tid < NSB) bsums[tid] = tmp[tid] - orig;
}

__global__ __launch_bounds__(256) void add_off_kernel(const int* __restrict__ excl,
                                                      const int* __restrict__ bsums,
                                                      int* __restrict__ seg_start,
                                                      int* __restrict__ cursor) {
    int i = blockIdx.x * 256 + threadIdx.x;
    if (i < MM) {
        int v = excl[i] + bsums[i >> 11];
        seg_start[i] = v;
        cursor[i] = v;
    }
    if (i == 0) seg_start[MM] = NE;
}

__global__ __launch_bounds__(256) void sort_scatter_kernel(
    const int* __restrict__ srcv, const int* __restrict__ dstv,
    const int* __restrict__ typev, int* __restrict__ cursor,
    int* __restrict__ esrc, int* __restrict__ eid) {
    int e = blockIdx.x * 256 + threadIdx.x;
    if (e < NE) {
        int key = dstv[e] * 8 + typev[e];
        int pos = atomicAdd(&cursor[key], 1);
        esrc[pos] = srcv[e];
        eid[pos]  = e;
    }
}

__global__ __launch_bounds__(256) void invdeg_kernel(const int* __restrict__ seg_start,
                                                     float* __restrict__ invdeg) {
    int i = blockIdx.x * 256 + threadIdx.x;
    if (i < NN) {
        int d = seg_start[i * 8 + 8] - seg_start[i * 8];
        invdeg[i] = 1.0f / (float)max(d, 1);
    }
}

// ---------------- once-per-call precomputes ----------------

__global__ __launch_bounds__(256) void eagg_kernel(
    const int* __restrict__ seg_start, const int* __restrict__ eid,
    const float* __restrict__ ee, const float* __restrict__ invdeg,
    unsigned short* __restrict__ eaggbf) {
    int tid = threadIdx.x;
    int s = blockIdx.x * 8 + (tid >> 5);
    int j = tid & 31;
    int n = s >> 3, r = s & 7;
    int j0 = seg_start[s], j1 = seg_start[s + 1];
    float sum = 0.0f;
    for (int p = j0; p < j1; ++p)
        sum += ee[eid[p] * EED + j];
    eaggbf[(size_t)n * DD + r * EED + j] = f2bf(sum * invdeg[n]);
}

// Whe split-K over 8 d-chunks of 32, fp32 atomics (Whe pre-zeroed)
__global__ __launch_bounds__(256) void whe_kernel(const float* __restrict__ We,
                                                  const float* __restrict__ W,
                                                  float* __restrict__ Whe) {
    __shared__ float WeS[EED * 32];
    int b = blockIdx.x;
    int l = b >> 6;
    int r = (b >> 3) & 7;
    int dc = b & 7;
    int tid = threadIdx.x;
    {
        int j = tid >> 3, dl = (tid & 7) * 4;
        *(float4*)&WeS[j * 32 + dl] =
            *(const float4*)&We[(size_t)l * EED * DD + (size_t)j * DD + dc * 32 + dl];
    }
    __syncthreads();
    const float* Wr = W + ((size_t)l * 8 + r) * DD * DD + (size_t)dc * 32 * DD;
    float acc[EED];
#pragma unroll
    for (int j = 0; j < EED; ++j) acc[j] = 0.0f;
    for (int dl = 0; dl < 32; ++dl) {
        float w = Wr[(size_t)dl * DD + tid];
#pragma unroll
        for (int j = 0; j < EED; ++j) acc[j] += WeS[j * 32 + dl] * w;
    }
    float* outp = Whe + (size_t)l * DD * DD + r * EED * DD + tid;
#pragma unroll
    for (int j = 0; j < EED; ++j) unsafeAtomicAdd(&outp[j * DD], acc[j]);
}

// B pre-swizzle into MFMA fragment order (bf16).
// Phase order: p=0 -> Wself, p=1..8 -> W[r=p-1], p=9 -> Whe.
// Bsw[l][(((p*8+kb)*4+quad)*256+f)*8+j] = B_l[p][kb*32+quad*8+j][f]
__global__ __launch_bounds__(256) void bswz_kernel(const float* __restrict__ W,
                                                   const float* __restrict__ Wself,
                                                   const float* __restrict__ Whe,
                                                   unsigned short* __restrict__ Bsw) {
    int gid = blockIdx.x * 256 + threadIdx.x;
    int f = gid & 255;
    int t = gid >> 8;
    int quad = t & 3; t >>= 2;
    int kb = t & 7; t >>= 3;
    int p = t % 10, l = t / 10;
    const float* base = (p == 0) ? Wself + (size_t)l * DD * DD
                      : (p <= 8) ? W + ((size_t)l * 8 + (p - 1)) * DD * DD
                                 : Whe + (size_t)l * DD * DD;
    int k0 = kb * 32 + quad * 8;
    unsigned pk[4];
#pragma unroll
    for (int jj = 0; jj < 4; ++jj)
        pk[jj] = pack2(base[(size_t)(k0 + 2 * jj) * DD + f],
                       base[(size_t)(k0 + 2 * jj + 1) * DD + f]);
    uint4 v = make_uint4(pk[0], pk[1], pk[2], pk[3]);
    *(uint4*)&Bsw[(size_t)gid * 8] = v;
}

__global__ __launch_bounds__(256) void init_x_kernel(float* __restrict__ x,
                                                     unsigned short* __restrict__ xbf) {
    int i = blockIdx.x * 256 + threadIdx.x;
    ((float4*)x)[i] = make_float4(1.f, 1.f, 1.f, 1.f);
    ((uint2*)xbf)[i] = make_uint2(0x3f803f80u, 0x3f803f80u);
}

// ------- fused per-layer kernel: producer/consumer waves, gather + MFMA + LN -------
// Block = 32 dst rows x 256 cols, 8 waves (512 thr):
//   waves 0..3 (CONSUMERS): MFMA on buf[p], cols cwave*64..+63, B fragments
//     register-prefetched 2 g-steps ahead from pre-swizzled Bsw.
//   waves 4..7 (PRODUCERS): cross-phase software pipeline. At iteration p they
//     ACCUMULATE the gather batch for phase p+1 (loads issued one phase earlier)
//     and immediately RE-ISSUE that row's 4 slots for the next relation, so every
//     batch gets a full phase (~consumer MFMA window) of latency budget.
// Phase barriers are raw s_barrier + lgkmcnt(0) only (NO vmcnt drain): in-flight
// gather loads and consumer B-prefetches survive the barrier (T14/m201 pattern).
// Rolling bounds: j1(rel r) == j0(rel r+1), so 1 LDS read per row per phase.
// eagg (phase 9) is staged once in the prologue into a 3rd buffer.
// LDS: 3x16KB phase buffers + 1040B bounds + ES_CAP*4 edge srcs = 55312B.
// __launch_bounds__(512,2): <=256 total regs. Round-1 lesson: (512,4) forced
// 64 VGPR -> gv[8][4] pipeline state spilled to scratch (WRITE_SIZE 40->359MB,
// 3.2x slower). Pipeline state needs ~190-220 regs; 1 block/CU is the ceiling.
__global__ __launch_bounds__(512, 2) void fused_layer_kernel(
    const int* __restrict__ seg_start, const int* __restrict__ esrc,
    const unsigned short* __restrict__ xbf, const unsigned short* __restrict__ eaggbf,
    const unsigned short* __restrict__ Bswl, const float* __restrict__ xin,
    const float* __restrict__ gl, const float* __restrict__ bl,
    float* __restrict__ xout, unsigned short* __restrict__ xbfout) {
    __shared__ __align__(16) unsigned char smem[49152 + 1040 + ES_CAP * 4];
    float* Hs = (float*)smem;                       // epilogue overlay (32 x HSTR)
    int* boundsS = (int*)(smem + 49152);            // 257 seg bounds
    int* esrcS   = (int*)(smem + 49152 + 1040);     // staged edge srcs
    int tid = threadIdx.x;
    int wave = tid >> 6, lane = tid & 63;
    bool consumer = wave < 4;
    int cwave = wave & 3;                           // consumer col group / producer row group
    int row0 = blockIdx.x * 32;
    int m = lane & 15, quad = lane >> 4;
    int colg = lane >> 1, half = lane & 1, cofs = lane * 4;
    f4 acc[2][4] = {};

    // ---- prologue: bounds, x tile, eagg tile, edge list, B prefetch ----
    if (tid < 257) {
        int idx = row0 * 8 + tid;
        boundsS[tid] = (idx <= MM) ? seg_start[idx] : NE;   // pad rows -> empty
    }
    uint4 xs[2];
#pragma unroll
    for (int c = 0; c < 2; ++c) {
        int i = tid + c * 512;
        int row = i >> 5, sc = i & 31;
        xs[c] = *(const uint4*)&xbf[(size_t)(row0 + row) * DD + sc * 8];
    }
    uint4 ev[4];
    if (!consumer) {
#pragma unroll
        for (int it = 0; it < 4; ++it) {
            int row = cwave * 8 + it * 2 + (lane >> 5);
            int sc = lane & 31;
            ev[it] = *(const uint4*)&eaggbf[(size_t)(row0 + row) * DD + sc * 8];
        }
    }
    __syncthreads();                                // bounds visible
    int blk0 = boundsS[0];
    int blkE = boundsS[256] - blk0;
    for (int j = tid; j < ES_CAP; j += 512)
        esrcS[j] = (j < blkE) ? esrc[blk0 + j] : 0; // always-valid node ids
#pragma unroll
    for (int c = 0; c < 2; ++c) {
        int i = tid + c * 512;
        int row = i >> 5, sc = i & 31;
        *(uint4*)&smem[row * 512 + ((sc ^ row) * 16)] = xs[c];     // x -> buf0
    }
    int jroll[8];
    float idgr[8];
    if (!consumer) {
#pragma unroll
        for (int it = 0; it < 4; ++it) {            // eagg -> buf2
            int row = cwave * 8 + it * 2 + (lane >> 5);
            int sc = lane & 31;
            *(uint4*)&smem[32768 + row * 512 + ((sc ^ row) * 16)] = ev[it];
        }
#pragma unroll
        for (int i8 = 0; i8 < 8; ++i8) {
            int nl = cwave * 8 + i8;
            jroll[i8] = boundsS[nl * 8] - blk0;     // j0 of relation 0
            int dg = boundsS[nl * 8 + 8] - boundsS[nl * 8];
            idgr[i8] = 1.0f / (float)max(dg, 1);
        }
    }
    bf8 breg[2][4];
    if (consumer) {
#pragma unroll
        for (int nt = 0; nt < 4; ++nt) {
            breg[0][nt] = *(const bf8*)&Bswl[((size_t)quad * 256 + cwave * 64 + nt * 16 + m) * 8];
            breg[1][nt] = *(const bf8*)&Bswl[((size_t)(4 + quad) * 256 + cwave * 64 + nt * 16 + m) * 8];
        }
    }
    __syncthreads();                                // esrcS + buf0 + buf2 visible

    // issue relation-0 gather batch (consumed at iteration p=0)
    uint2 gv[8][4];
    if (!consumer) {
#pragma unroll
        for (int i8 = 0; i8 < 8; ++i8) {
#pragma unroll
            for (int s = 0; s < 4; ++s) {
                int jc = jroll[i8] + s;
                jc = (jc < ES_CAP) ? jc : (ES_CAP - 1);
                gv[i8][s] = *(const uint2*)&xbf[(size_t)esrcS[jc] * DD + cofs];
            }
        }
    }

#pragma unroll
    for (int p = 0; p < 10; ++p) {
        if (consumer) {
            // ---- 8 MFMA steps on buf[p]; B register-prefetch 2 steps ahead ----
            unsigned char* bufp = smem + ((p == 9) ? 2 : (p & 1)) * 16384;
#pragma unroll
            for (int kb = 0; kb < 8; ++kb) {
                bf8 afr[2];
#pragma unroll
                for (int mt = 0; mt < 2; ++mt) {
                    int rowl = mt * 16 + m;
                    afr[mt] = *(bf8*)&bufp[rowl * 512 + (((kb * 4 + quad) ^ rowl) * 16)];
                }
#pragma unroll
                for (int mt = 0; mt < 2; ++mt)
#pragma unroll
                    for (int nt = 0; nt < 4; ++nt)
                        acc[mt][nt] = __builtin_amdgcn_mfma_f32_16x16x32_bf16(
                            afr[mt], breg[kb & 1][nt], acc[mt][nt], 0, 0, 0);
                int gn = p * 8 + kb + 2;
                if (gn < 80) {
#pragma unroll
                    for (int nt = 0; nt < 4; ++nt)
                        breg[kb & 1][nt] = *(const bf8*)&Bswl[((size_t)gn * 4 + quad) * 2048
                                                              + ((size_t)(cwave * 64 + nt * 16 + m)) * 8];
                }
            }
        } else if (p < 8) {
            // ---- producer: finish relation p (phase q=p+1) into buf[q&1];
            //      per row, immediately re-issue next relation's 4 slots ----
            int q = p + 1;
            unsigned char* bufn = smem + ((q & 1) * 16384);
#pragma unroll
            for (int i8 = 0; i8 < 8; ++i8) {
                int nl = cwave * 8 + i8;
                int j0 = jroll[i8];
                int j1 = boundsS[nl * 8 + q] - blk0;   // end of relation p = start of p+1
                float a0 = 0.f, a1 = 0.f, a2 = 0.f, a3 = 0.f;
#pragma unroll
                for (int s = 0; s < 4; ++s) {
                    unsigned vx = (j0 + s < j1) ? gv[i8][s].x : 0u;
                    unsigned vy = (j0 + s < j1) ? gv[i8][s].y : 0u;
                    a0 += lo2f(vx); a1 += hi2f(vx);
                    a2 += lo2f(vy); a3 += hi2f(vy);
                }
                if (q < 8) {                            // issue next-relation batch
#pragma unroll
                    for (int s = 0; s < 4; ++s) {
                        int jc = j1 + s;
                        jc = (jc < ES_CAP) ? jc : (ES_CAP - 1);
                        gv[i8][s] = *(const uint2*)&xbf[(size_t)esrcS[jc] * DD + cofs];
                    }
                }
                for (int j = j0 + 4; j < j1; ++j) {     // rare tail (>4 edges/seg)
                    int src = (j < ES_CAP) ? esrcS[j] : esrc[blk0 + j];
                    uint2 v = *(const uint2*)&xbf[(size_t)src * DD + cofs];
                    a0 += lo2f(v.x); a1 += hi2f(v.x);
                    a2 += lo2f(v.y); a3 += hi2f(v.y);
                }
                float idg = idgr[i8];
                *(uint2*)&bufn[nl * 512 + ((colg ^ nl) * 16) + half * 8] =
                    make_uint2(pack2(a0 * idg, a1 * idg), pack2(a2 * idg, a3 * idg));
                jroll[i8] = j1;
            }
        }
        // raw phase barrier: drain LDS writes only, keep VMEM (gathers + B prefetch)
        // in flight across the barrier. sched_barrier fences scheduler motion (#18).
        asm volatile("s_waitcnt lgkmcnt(0)" ::: "memory");
        __builtin_amdgcn_s_barrier();
        __builtin_amdgcn_sched_barrier(0);
    }

    // ---- epilogue: residual prefetch; h tile through LDS; LN+ReLU+residual ----
    float4 xvr[4];
#pragma unroll
    for (int rr = 0; rr < 4; ++rr) {
        int row = wave * 4 + rr;
        xvr[rr] = *(const float4*)&xin[(size_t)(row0 + row) * DD + lane * 4];
    }
    float4 g  = *(const float4*)&gl[lane * 4];
    float4 bb = *(const float4*)&bl[lane * 4];
    if (consumer) {
#pragma unroll
        for (int mt = 0; mt < 2; ++mt)
#pragma unroll
            for (int nt = 0; nt < 4; ++nt)
#pragma unroll
                for (int rg = 0; rg < 4; ++rg)
                    Hs[(mt * 16 + quad * 4 + rg) * HSTR + cwave * 64 + nt * 16 + m] = acc[mt][nt][rg];
    }
    __syncthreads();
#pragma unroll
    for (int rr = 0; rr < 4; ++rr) {
        int row = wave * 4 + rr;
        float4 v = *(float4*)&Hs[row * HSTR + lane * 4];
        float s = v.x + v.y + v.z + v.w;
        float q = v.x * v.x + v.y * v.y + v.z * v.z + v.w * v.w;
#pragma unroll
        for (int off = 32; off; off >>= 1) {
            s += __shfl_xor(s, off);
            q += __shfl_xor(q, off);
        }
        float mu  = s * (1.0f / DD);
        float var = q * (1.0f / DD) - mu * mu;
        float rs  = rsqrtf(var + 1e-5f);
        size_t xi = (size_t)(row0 + row) * DD + lane * 4;
        float4 xv = xvr[rr];
        float4 o;
        o.x = fmaxf((v.x - mu) * rs * g.x + bb.x, 0.0f) + xv.x;
        o.y = fmaxf((v.y - mu) * rs * g.y + bb.y, 0.0f) + xv.y;
        o.z = fmaxf((v.z - mu) * rs * g.z + bb.z, 0.0f) + xv.z;
        o.w = fmaxf((v.w - mu) * rs * g.w + bb.w, 0.0f) + xv.w;
        *(float4*)&xout[xi] = o;
        *(uint2*)&xbfout[xi] = make_uint2(pack2(o.x, o.y), pack2(o.z, o.w));
    }
}

__global__ __launch_bounds__(256) void score_kernel(
    const int* __restrict__ batch, const float* __restrict__ x,
    const float* __restrict__ rel_emb, float* __restrict__ out) {
    int tid = threadIdx.x;
    int wave = tid >> 6, lane = tid & 63;
    int idx = blockIdx.x * 4 + wave;
    int s = batch[idx * 3 + 0], t = batch[idx * 3 + 1], r = batch[idx * 3 + 2];
    float4 sv = *(const float4*)&x[(size_t)s * DD + lane * 4];
    float4 tv = *(const float4*)&x[(size_t)t * DD + lane * 4];
    float4 rv = *(const float4*)&rel_emb[(size_t)r * DD + lane * 4];
    float sum = sv.x * rv.x * tv.x + sv.y * rv.y * tv.y +
                sv.z * rv.z * tv.z + sv.w * rv.w * tv.w;
#pragma unroll
    for (int off = 32; off; off >>= 1) sum += __shfl_xor(sum, off);
    if (lane == 0) out[idx] = sum;
}

extern "C" void kernel_launch(void* const* d_in, const int* in_sizes, int n_in,
                              void* d_out, int out_size, void* d_ws, size_t ws_size,
                              hipStream_t stream) {
    const int*   edge_index = (const int*)d_in[0];
    const int*   srcv   = edge_index;
    const int*   dstv   = edge_index + NE;
    const int*   typev  = (const int*)d_in[1];
    const float* ee     = (const float*)d_in[2];
    const int*   batch  = (const int*)d_in[3];
    const float* W      = (const float*)d_in[4];
    const float* Wself  = (const float*)d_in[5];
    const float* We     = (const float*)d_in[6];
    const float* gamma  = (const float*)d_in[7];
    const float* beta   = (const float*)d_in[8];
    const float* rel_emb= (const float*)d_in[9];
    float* out = (float*)d_out;

    // workspace layout
    float* xA     = (float*)d_ws;                          // NP*256 f32
    float* xB     = xA + (size_t)NP * DD;                  // NP*256 f32
    float* Whe    = xB + (size_t)NP * DD;                  // L*256*256 f32
    float* invdeg = Whe + (size_t)LL * DD * DD;            // NN f32
    unsigned short* xbfA   = (unsigned short*)(invdeg + NN);          // NP*256
    unsigned short* xbfB   = xbfA + (size_t)NP * DD;                  // NP*256
    unsigned short* eaggbf = xbfB + (size_t)NP * DD;                  // NP*256
    unsigned short* Bsw    = eaggbf + (size_t)NP * DD;                // L*2560*256
    int* hist      = (int*)(Bsw + (size_t)LL * 2560 * DD);            // M
    int* excl      = hist + MM;
    int* seg_start = excl + MM;                                       // M+1
    int* cursor    = seg_start + MM + 1;
    int* bsums     = cursor + MM;                                     // 256
    int* esrc      = bsums + 256;                                     // E
    int* eid       = esrc + NE;                                       // E

    // ---- CSR build ----
    hipMemsetAsync(hist, 0, MM * sizeof(int), stream);
    hist_kernel<<<(NE + 255) / 256, 256, 0, stream>>>(dstv, typev, hist);
    scan1_kernel<<<NSB, 256, 0, stream>>>(hist, excl, bsums);
    scan2_kernel<<<1, 128, 0, stream>>>(bsums);
    add_off_kernel<<<(MM + 255) / 256, 256, 0, stream>>>(excl, bsums, seg_start, cursor);
    invdeg_kernel<<<(NN + 255) / 256, 256, 0, stream>>>(seg_start, invdeg);
    sort_scatter_kernel<<<(NE + 255) / 256, 256, 0, stream>>>(srcv, dstv, typev, cursor, esrc, eid);

    // ---- precomputes ----
    eagg_kernel<<<MM / 8, 256, 0, stream>>>(seg_start, eid, ee, invdeg, eaggbf);
    hipMemsetAsync(Whe, 0, (size_t)LL * DD * DD * sizeof(float), stream);
    whe_kernel<<<LL * 64, 256, 0, stream>>>(We, W, Whe);
    bswz_kernel<<<LL * 10 * 8 * 4, 256, 0, stream>>>(W, Wself, Whe, Bsw);
    init_x_kernel<<<(NP * DD / 4) / 256, 256, 0, stream>>>(xA, xbfA);

    // ---- layers (x double-buffered), producer/consumer fused kernel ----
    float* xin = xA;  float* xout = xB;
    unsigned short* xbin = xbfA;  unsigned short* xbout = xbfB;
    for (int l = 0; l < LL; ++l) {
        fused_layer_kernel<<<NB2, 512, 0, stream>>>(seg_start, esrc, xbin, eaggbf,
            Bsw + (size_t)l * 2560 * DD, xin,
            gamma + (size_t)l * DD, beta + (size_t)l * DD, xout, xbout);
        float* t = xin; xin = xout; xout = t;
        unsigned short* tb = xbin; xbin = xbout; xbout = tb;
    }
    score_kernel<<<(BB * KK) / 4, 256, 0, stream>>>(batch, xin, rel_emb, out);
}